// Round 13
// baseline (820.144 us; speedup 1.0000x reference)
//
#include <hip/hip_runtime.h>

// IcoPool: out[b,f,v] = mean_{k<7} x[b,f,idx[v,k]]
// x: (8, 64, 163842) f32, idx: (40962, 7) int32, out: (8, 64, 40962) f32
//
// Model (r0-r12): gather requests = gathered_bytes/16B = 18.3M invariant.
//   L2-hit service ~0.27 req/cyc/CU, fabric ~0.19 and latency-capped.
//   v12 (RG=8, L2-resident window) = 540.7us total; pack ~100us BW-bound,
//   gather ~135us request-bound, SERIALIZED -> complementary resources idle.
// v13: fuse. One kernel; group g packed AND gathered by XCD g/8 (same L2 ->
//   dirty-line coherence, no fences that invalidate). 161 blocks/group: each
//   packs 1/161 of the columns, releases via vmcnt(0)+barrier+atomicAdd on a
//   64B-padded per-group flag, spins (t0 + s_sleep) until 161, then gathers
//   its v-block (v12 path). Per-XCD FIFO dispatch + 256 resident blocks/XCD
//   >= 162 -> oldest group always completes: no deadlock. Flags pre-zeroed
//   by a tiny kernel (ws is poisoned).

typedef float    f4v __attribute__((ext_vector_type(4)));
typedef float    f8  __attribute__((ext_vector_type(8)));
typedef _Float16 h8  __attribute__((ext_vector_type(8)));
typedef unsigned int u4 __attribute__((ext_vector_type(4)));

constexpr int B = 8, F = 64, V_IN = 163842, V_OUT = 40962, K = 7;
constexpr int ROWS = B * F;                         // 512
constexpr int RG   = 8;                             // rows per entry (16 B fp16)
constexpr int NG   = ROWS / RG;                     // 64 groups
constexpr int TPB  = 256;
constexpr int GPX  = NG / 8;                        // 8 groups per XCD
constexpr int VB   = (V_OUT + TPB - 1) / TPB;       // 161 v-blocks (= pack chunks)
constexpr int CPG  = 1020;                          // pack cols per chunk (x4 aligned; 161*1020 >= V_IN)
constexpr int BLOCKS = NG * VB;                     // 10304
constexpr size_t XH_BYTES  = (size_t)NG * V_IN * 16; // 167.8 MB
constexpr size_t FLAGS_OFF = (XH_BYTES + 255) & ~(size_t)255;
constexpr int FLAG_STRIDE  = 16;                    // ints; 64B per group (no false sharing)
constexpr size_t WS_NEED   = FLAGS_OFF + (size_t)NG * FLAG_STRIDE * 4;

__global__ __launch_bounds__(64) void icopool_zero(int* __restrict__ flags)
{
    flags[threadIdx.x * FLAG_STRIDE] = 0;
}

// ---- fused pack + gather, per-group producer->consumer on one XCD ----
__global__ __launch_bounds__(TPB) void icopool_fused(
    const float* __restrict__ x,
    u4*          __restrict__ xH,
    int*         __restrict__ flags,
    const int*   __restrict__ nidx,
    float*       __restrict__ out)
{
    __shared__ int sidx[TPB * K];                   // 7168 B
    const int bid = blockIdx.x;
    const int xcd = bid & 7;             // HW round-robin XCD assignment
    const int j   = bid >> 3;
    const int gl  = j / VB;              // group within XCD (slow)
    const int vb  = j % VB;              // v-block & pack-chunk (fast)
    const int g   = xcd * GPX + gl;
    const int t   = threadIdx.x;

    // ---------- pack phase: cols [vb*CPG, (vb+1)*CPG) of group g ----------
    {
        const int c0 = vb * CPG + t * 4;
        const int cend = (vb + 1) * CPG;
        if (c0 < cend && c0 < V_IN) {
            const float* xg = x + (size_t)g * RG * V_IN;
            if (c0 + 3 < V_IN) {
                h8 e0, e1, e2, e3;
                #pragma unroll
                for (int r = 0; r < RG; ++r) {
                    const f4v vv = __builtin_nontemporal_load(
                        (const f4v*)(xg + (size_t)r * V_IN + c0));
                    e0[r] = (_Float16)vv.x;
                    e1[r] = (_Float16)vv.y;
                    e2[r] = (_Float16)vv.z;
                    e3[r] = (_Float16)vv.w;
                }
                union { h8 h; u4 u; } u0, u1, u2, u3;
                u0.h = e0; u1.h = e1; u2.h = e2; u3.h = e3;
                u4* dst = xH + (size_t)g * V_IN + c0;
                dst[0] = u0.u;                       // regular stores: stay in L2
                dst[1] = u1.u;
                dst[2] = u2.u;
                dst[3] = u3.u;
            } else {
                #pragma unroll
                for (int cc = 0; cc < 4; ++cc) {
                    const int c = c0 + cc;
                    if (c < V_IN) {
                        h8 e;
                        #pragma unroll
                        for (int r = 0; r < RG; ++r)
                            e[r] = (_Float16)xg[(size_t)r * V_IN + c];
                        union { h8 h; u4 u; } cv; cv.h = e;
                        xH[(size_t)g * V_IN + c] = cv.u;
                    }
                }
            }
        }
    }

    // stage idx (coalesced) while pack stores drain
    const int fbase = vb * (TPB * K);
    #pragma unroll
    for (int k = 0; k < K; ++k) {
        const int off = k * TPB + t;
        sidx[off] = (fbase + off < V_OUT * K) ? nidx[fbase + off] : 0;
    }

    // ---------- release + spin: group g fully packed? ----------
    asm volatile("s_waitcnt vmcnt(0)" ::: "memory"); // per-wave: stores are in L2
    __syncthreads();                                  // whole block released
    if (t == 0) {
        int* fp = flags + g * FLAG_STRIDE;
        __hip_atomic_fetch_add(fp, 1, __ATOMIC_RELAXED, __HIP_MEMORY_SCOPE_AGENT);
        while (__hip_atomic_load(fp, __ATOMIC_RELAXED, __HIP_MEMORY_SCOPE_AGENT) < VB)
            __builtin_amdgcn_s_sleep(8);
    }
    __syncthreads();

    // ---------- gather phase (v12): one 16B entry load per (v,k) ----------
    const int v = vb * TPB + t;
    if (v >= V_OUT) return;

    const int* my = sidx + t * K;
    const u4* s = xH + (size_t)g * V_IN;
    const u4 q0 = s[(size_t)my[0]];
    const u4 q1 = s[(size_t)my[1]];
    const u4 q2 = s[(size_t)my[2]];
    const u4 q3 = s[(size_t)my[3]];
    const u4 q4 = s[(size_t)my[4]];
    const u4 q5 = s[(size_t)my[5]];
    const u4 q6 = s[(size_t)my[6]];

    union { u4 u; h8 h; } c0, c1, c2, c3, c4, c5, c6;
    c0.u = q0; c1.u = q1; c2.u = q2; c3.u = q3; c4.u = q4; c5.u = q5; c6.u = q6;
    f8 acc = __builtin_convertvector(c0.h, f8);
    acc += __builtin_convertvector(c1.h, f8);
    acc += __builtin_convertvector(c2.h, f8);
    acc += __builtin_convertvector(c3.h, f8);
    acc += __builtin_convertvector(c4.h, f8);
    acc += __builtin_convertvector(c5.h, f8);
    acc += __builtin_convertvector(c6.h, f8);
    acc *= (1.0f / 7.0f);

    float* o = out + (size_t)(g * RG) * V_OUT + v;
    #pragma unroll
    for (int rr = 0; rr < 8; ++rr)
        __builtin_nontemporal_store(acc[rr], o + (size_t)rr * V_OUT);
}

// ---------------- fallback (v1): direct gather, no workspace ----------------
constexpr int RPB  = 2;
constexpr int RGS  = ROWS / RPB;
constexpr int RG_PER_XCD = RGS / 8;
constexpr int VB1  = (V_OUT + TPB - 1) / TPB;
constexpr int BLOCKS_V1  = RGS * VB1;

__global__ __launch_bounds__(TPB) void icopool_gather(
    const float* __restrict__ x,
    const int*   __restrict__ nidx,
    float*       __restrict__ out)
{
    const int b        = blockIdx.x;
    const int xcd      = b & 7;
    const int j        = b >> 3;
    const int rg_local = j / VB1;
    const int vb       = j % VB1;
    const int rg       = xcd * RG_PER_XCD + rg_local;
    const int r0       = rg * RPB;

    const int v = vb * TPB + threadIdx.x;
    if (v >= V_OUT) return;

    const int base = v * K;
    const int i0 = nidx[base + 0];
    const int i1 = nidx[base + 1];
    const int i2 = nidx[base + 2];
    const int i3 = nidx[base + 3];
    const int i4 = nidx[base + 4];
    const int i5 = nidx[base + 5];
    const int i6 = nidx[base + 6];

    #pragma unroll
    for (int r = 0; r < RPB; ++r) {
        const float* xr = x + (size_t)(r0 + r) * V_IN;
        float sum = xr[i0] + xr[i1] + xr[i2] + xr[i3] + xr[i4] + xr[i5] + xr[i6];
        __builtin_nontemporal_store(sum * (1.0f / 7.0f),
                                    out + (size_t)(r0 + r) * V_OUT + v);
    }
}

extern "C" void kernel_launch(void* const* d_in, const int* in_sizes, int n_in,
                              void* d_out, int out_size, void* d_ws, size_t ws_size,
                              hipStream_t stream) {
    const float* x    = (const float*)d_in[0];
    const int*   nidx = (const int*)d_in[1];
    float*       out  = (float*)d_out;

    if (ws_size >= WS_NEED && d_ws != nullptr) {
        u4*  xH    = (u4*)d_ws;
        int* flags = (int*)((char*)d_ws + FLAGS_OFF);
        icopool_zero<<<dim3(1), dim3(64), 0, stream>>>(flags);
        icopool_fused<<<dim3(BLOCKS), dim3(TPB), 0, stream>>>(x, xH, flags, nidx, out);
    } else {
        icopool_gather<<<dim3(BLOCKS_V1), dim3(TPB), 0, stream>>>(x, nidx, out);
    }
}

// Round 14
// 550.004 us; speedup vs baseline: 1.4912x; 1.4912x over previous
//
#include <hip/hip_runtime.h>

// IcoPool: out[b,f,v] = mean_{k<7} x[b,f,idx[v,k]]
// x: (8, 64, 163842) f32, idx: (40962, 7) int32, out: (8, 64, 40962) f32
//
// Model (r0-r13): gather requests = gathered_bytes/16B = 18.3M invariant.
//   L2-hit service ~0.27 req/cyc/CU; fabric ~0.19 latency-capped; partial-line
//   entries pay 2x (v11); L3 residency irrelevant (v10); nt gather loads hurt
//   (v9); pack/gather fusion destroys L2 residency + serializes on spin (v13,
//   488us fused vs 235us split -> REVERTED).
// v12 (best, 540.7us): RG=8 16B entries (one full lane req), group-outer
//   phases, occupancy capped 4 blocks/CU via LDS limiter -> live window
//   ~3.4MB < 4MB per-XCD L2 -> gather in the L2-hit regime (~135us).
// v14: v12 + pack upgraded to f4 nt-reads 4 cols/thread (v13's pack layout,
//   proven correct there): 16B/lane reads instead of 8B. Gather unchanged.

typedef float    f4v __attribute__((ext_vector_type(4)));
typedef float    f8  __attribute__((ext_vector_type(8)));
typedef _Float16 h8  __attribute__((ext_vector_type(8)));
typedef unsigned int u4 __attribute__((ext_vector_type(4)));

constexpr int B = 8, F = 64, V_IN = 163842, V_OUT = 40962, K = 7;
constexpr int ROWS = B * F;                        // 512
constexpr int RG   = 8;                            // rows per entry (16 B fp16)
constexpr int NG   = ROWS / RG;                    // 64 groups
constexpr int TPB  = 256;
constexpr int GPX  = NG / 8;                       // 8 groups per XCD
// pass 1
constexpr int CPB1 = 4 * TPB;                      // 1024 cols per block
constexpr int IBX  = (V_IN + CPB1 - 1) / CPB1;     // 161
// pass 2
constexpr int VB   = (V_OUT + TPB - 1) / TPB;      // 161 v-blocks per group
constexpr int BLOCKS2 = 8 * GPX * VB;              // 10304
constexpr size_t XH_BYTES = (size_t)NG * V_IN * 16; // 167.8 MB

// ---- pass 1: pack 8 f32 rows -> 16B fp16 entries (no LDS, f4 reads) ----
// lane t: cols c0..c0+3. Reads: 8 rows x f4 nt (16B/lane, coalesced 1KB/wave;
// x is read exactly once). Writes: 4 full 16B entries, regular stores (v8
// lesson: let the slab allocate in cache).
__global__ __launch_bounds__(TPB) void icopool_pack_h8(
    const float* __restrict__ x, u4* __restrict__ xH)
{
    const int g  = blockIdx.y;
    const int c0 = blockIdx.x * CPB1 + threadIdx.x * 4;
    if (c0 >= V_IN) return;
    const float* xg = x + (size_t)g * RG * V_IN;

    if (c0 + 3 < V_IN) {
        h8 e0, e1, e2, e3;
        #pragma unroll
        for (int r = 0; r < RG; ++r) {
            const f4v vv = __builtin_nontemporal_load(
                (const f4v*)(xg + (size_t)r * V_IN + c0));
            e0[r] = (_Float16)vv.x;
            e1[r] = (_Float16)vv.y;
            e2[r] = (_Float16)vv.z;
            e3[r] = (_Float16)vv.w;
        }
        union { h8 h; u4 u; } u0, u1, u2, u3;
        u0.h = e0; u1.h = e1; u2.h = e2; u3.h = e3;
        u4* dst = xH + (size_t)g * V_IN + c0;
        dst[0] = u0.u;
        dst[1] = u1.u;
        dst[2] = u2.u;
        dst[3] = u3.u;
    } else {
        #pragma unroll
        for (int cc = 0; cc < 4; ++cc) {
            const int c = c0 + cc;
            if (c < V_IN) {
                h8 e;
                #pragma unroll
                for (int r = 0; r < RG; ++r)
                    e[r] = (_Float16)xg[(size_t)r * V_IN + c];
                union { h8 h; u4 u; } cv; cv.h = e;
                xH[(size_t)g * V_IN + c] = cv.u;
            }
        }
    }
}

// ---- pass 2: L2-resident gather. One 16B entry load per (v,k). ----
// Occupancy deliberately capped at 4 blocks/CU by the LDS footprint (~40KB):
// resident cohort 128 blocks/XCD < 161 blocks/phase -> only ~1.3 group slabs
// (3.4MB) live per XCD L2 at any time. idx staged coalesced through LDS.
__global__ __launch_bounds__(TPB) void icopool_gather_h8(
    const u4* __restrict__ xH,
    const int* __restrict__ nidx,
    float*     __restrict__ out)
{
    __shared__ int sidx[TPB * K];                  // 7168 B
    __shared__ int limiter[8192];                  // 32768 B -> 4 blocks/CU cap
    const int b   = blockIdx.x;
    const int xcd = b & 7;               // HW round-robin XCD assignment
    const int j   = b >> 3;
    const int gl  = j / VB;              // group within XCD (slow)
    const int vb  = j % VB;              // v-block (fast -> slab stays hot)
    const int t   = threadIdx.x;

    // coalesced idx stage: flat copy of this v-block's 1792 ints
    const int fbase = vb * (TPB * K);
    #pragma unroll
    for (int k = 0; k < K; ++k) {
        const int off = k * TPB + t;
        sidx[off] = (fbase + off < V_OUT * K) ? nidx[fbase + off] : 0;
    }
    if (t == 0) limiter[0] = 1;          // keep limiter allocation live
    __syncthreads();

    const int v = vb * TPB + t;
    if (v >= V_OUT) return;
    const int g = xcd * GPX + gl;

    const int* my = sidx + t * K;
    const u4* s = xH + (size_t)g * V_IN;
    const u4 q0 = s[(size_t)my[0]];
    const u4 q1 = s[(size_t)my[1]];
    const u4 q2 = s[(size_t)my[2]];
    const u4 q3 = s[(size_t)my[3]];
    const u4 q4 = s[(size_t)my[4]];
    const u4 q5 = s[(size_t)my[5]];
    const u4 q6 = s[(size_t)my[6]];

    union { u4 u; h8 h; } c0, c1, c2, c3, c4, c5, c6;
    c0.u = q0; c1.u = q1; c2.u = q2; c3.u = q3; c4.u = q4; c5.u = q5; c6.u = q6;
    f8 acc = __builtin_convertvector(c0.h, f8);
    acc += __builtin_convertvector(c1.h, f8);
    acc += __builtin_convertvector(c2.h, f8);
    acc += __builtin_convertvector(c3.h, f8);
    acc += __builtin_convertvector(c4.h, f8);
    acc += __builtin_convertvector(c5.h, f8);
    acc += __builtin_convertvector(c6.h, f8);
    acc *= (1.0f / 7.0f);

    float* o = out + (size_t)(g * RG) * V_OUT + v;
    #pragma unroll
    for (int rr = 0; rr < 8; ++rr)
        __builtin_nontemporal_store(acc[rr], o + (size_t)rr * V_OUT);
}

// ---------------- fallback (v1): direct gather, no workspace ----------------
constexpr int RPB  = 2;
constexpr int RGS  = ROWS / RPB;
constexpr int RG_PER_XCD = RGS / 8;
constexpr int VB1  = (V_OUT + TPB - 1) / TPB;
constexpr int BLOCKS_V1  = RGS * VB1;

__global__ __launch_bounds__(TPB) void icopool_gather(
    const float* __restrict__ x,
    const int*   __restrict__ nidx,
    float*       __restrict__ out)
{
    const int b        = blockIdx.x;
    const int xcd      = b & 7;
    const int j        = b >> 3;
    const int rg_local = j / VB1;
    const int vb       = j % VB1;
    const int rg       = xcd * RG_PER_XCD + rg_local;
    const int r0       = rg * RPB;

    const int v = vb * TPB + threadIdx.x;
    if (v >= V_OUT) return;

    const int base = v * K;
    const int i0 = nidx[base + 0];
    const int i1 = nidx[base + 1];
    const int i2 = nidx[base + 2];
    const int i3 = nidx[base + 3];
    const int i4 = nidx[base + 4];
    const int i5 = nidx[base + 5];
    const int i6 = nidx[base + 6];

    #pragma unroll
    for (int r = 0; r < RPB; ++r) {
        const float* xr = x + (size_t)(r0 + r) * V_IN;
        float sum = xr[i0] + xr[i1] + xr[i2] + xr[i3] + xr[i4] + xr[i5] + xr[i6];
        __builtin_nontemporal_store(sum * (1.0f / 7.0f),
                                    out + (size_t)(r0 + r) * V_OUT + v);
    }
}

extern "C" void kernel_launch(void* const* d_in, const int* in_sizes, int n_in,
                              void* d_out, int out_size, void* d_ws, size_t ws_size,
                              hipStream_t stream) {
    const float* x    = (const float*)d_in[0];
    const int*   nidx = (const int*)d_in[1];
    float*       out  = (float*)d_out;

    if (ws_size >= XH_BYTES && d_ws != nullptr) {
        u4* xH = (u4*)d_ws;
        icopool_pack_h8<<<dim3(IBX, NG), dim3(TPB), 0, stream>>>(x, xH);
        icopool_gather_h8<<<dim3(BLOCKS2), dim3(TPB), 0, stream>>>(xH, nidx, out);
    } else {
        icopool_gather<<<dim3(BLOCKS_V1), dim3(TPB), 0, stream>>>(x, nidx, out);
    }
}

// Round 15
// 541.250 us; speedup vs baseline: 1.5153x; 1.0162x over previous
//
#include <hip/hip_runtime.h>

// IcoPool: out[b,f,v] = mean_{k<7} x[b,f,idx[v,k]]
// x: (8, 64, 163842) f32, idx: (40962, 7) int32, out: (8, 64, 40962) f32
//
// FINAL (v12, session best 540.7us). Model (r0-r14):
//   gather requests = gathered_bytes/16B = 18.3M invariant; L2-hit service
//   ~0.27 req/cyc/CU; fabric ~0.19 latency-capped (L3 residency irrelevant,
//   v10); partial-line entries pay 2x (v11); nt gather loads hurt (v9);
//   deeper per-thread MLP null (v7); pack read-width null (v14); fusion
//   destroys L2 residency + spin-serializes (v13).
// Structure: fp16 slab, RG=8 -> 16B entry = one full lane request;
//   group-outer phases (8 groups/XCD, vb fastest); gather occupancy capped
//   at 4 blocks/CU via LDS limiter -> live window ~1.3 slabs ~3.4MB < 4MB
//   per-XCD L2 -> gather runs in the L2-hit regime (~135us). Pack ~100us at
//   its mixed-stream BW floor. Harness overhead ~305us (incl. 204us ws fill).

typedef float    f2 __attribute__((ext_vector_type(2)));
typedef float    f8 __attribute__((ext_vector_type(8)));
typedef _Float16 h8 __attribute__((ext_vector_type(8)));
typedef unsigned int u4 __attribute__((ext_vector_type(4)));

constexpr int B = 8, F = 64, V_IN = 163842, V_OUT = 40962, K = 7;
constexpr int ROWS = B * F;                        // 512
constexpr int RG   = 8;                            // rows per entry (16 B fp16)
constexpr int NG   = ROWS / RG;                    // 64 groups
constexpr int TPB  = 256;
constexpr int GPX  = NG / 8;                       // 8 groups per XCD
// pass 1
constexpr int CPB1 = 2 * TPB;                      // 512 cols per block
constexpr int IBX  = (V_IN + CPB1 - 1) / CPB1;     // 321
// pass 2
constexpr int VB   = (V_OUT + TPB - 1) / TPB;      // 161 v-blocks per group
constexpr int BLOCKS2 = 8 * GPX * VB;              // 10304
constexpr size_t XH_BYTES = (size_t)NG * V_IN * 16; // 167.8 MB

// ---- pass 1: pack 8 f32 rows -> 16B fp16 entries (no LDS) ----
// lane t: cols c0, c0+1. Reads: 8 rows x f2, coalesced 512B/wave, nt (x is
// read once). Writes: 2 full entries (16B each), regular (let the slab
// allocate in cache).
__global__ __launch_bounds__(TPB) void icopool_pack_h8(
    const float* __restrict__ x, u4* __restrict__ xH)
{
    const int g  = blockIdx.y;
    const int c0 = blockIdx.x * CPB1 + threadIdx.x * 2;
    if (c0 >= V_IN) return;
    const float* xp = x + (size_t)g * RG * V_IN + c0;
    h8 e0, e1;
    #pragma unroll
    for (int r = 0; r < 8; ++r) {
        const f2 v = __builtin_nontemporal_load((const f2*)(xp + (size_t)r * V_IN));
        e0[r] = (_Float16)v.x;
        e1[r] = (_Float16)v.y;
    }
    union { h8 h; u4 u; } cv0, cv1;
    cv0.h = e0; cv1.h = e1;
    u4* dst = xH + ((size_t)g * V_IN + c0);
    dst[0] = cv0.u;
    dst[1] = cv1.u;
}

// ---- pass 2: L2-resident gather. One 16B entry load per (v,k). ----
// Occupancy deliberately capped at 4 blocks/CU by the LDS footprint (~40KB):
// resident cohort 128 blocks/XCD < 161 blocks/phase -> only ~1.3 group slabs
// (3.4MB) live per XCD L2 at any time. idx staged coalesced through LDS.
__global__ __launch_bounds__(TPB) void icopool_gather_h8(
    const u4* __restrict__ xH,
    const int* __restrict__ nidx,
    float*     __restrict__ out)
{
    __shared__ int sidx[TPB * K];                  // 7168 B
    __shared__ int limiter[8192];                  // 32768 B -> 4 blocks/CU cap
    const int b   = blockIdx.x;
    const int xcd = b & 7;               // HW round-robin XCD assignment
    const int j   = b >> 3;
    const int gl  = j / VB;              // group within XCD (slow)
    const int vb  = j % VB;              // v-block (fast -> slab stays hot)
    const int t   = threadIdx.x;

    // coalesced idx stage: flat copy of this v-block's 1792 ints
    const int fbase = vb * (TPB * K);
    #pragma unroll
    for (int k = 0; k < K; ++k) {
        const int off = k * TPB + t;
        sidx[off] = (fbase + off < V_OUT * K) ? nidx[fbase + off] : 0;
    }
    if (t == 0) limiter[0] = 1;          // keep limiter allocation live
    __syncthreads();

    const int v = vb * TPB + t;
    if (v >= V_OUT) return;
    const int g = xcd * GPX + gl;

    const int* my = sidx + t * K;
    const u4* s = xH + (size_t)g * V_IN;
    const u4 q0 = s[(size_t)my[0]];
    const u4 q1 = s[(size_t)my[1]];
    const u4 q2 = s[(size_t)my[2]];
    const u4 q3 = s[(size_t)my[3]];
    const u4 q4 = s[(size_t)my[4]];
    const u4 q5 = s[(size_t)my[5]];
    const u4 q6 = s[(size_t)my[6]];

    union { u4 u; h8 h; } c0, c1, c2, c3, c4, c5, c6;
    c0.u = q0; c1.u = q1; c2.u = q2; c3.u = q3; c4.u = q4; c5.u = q5; c6.u = q6;
    f8 acc = __builtin_convertvector(c0.h, f8);
    acc += __builtin_convertvector(c1.h, f8);
    acc += __builtin_convertvector(c2.h, f8);
    acc += __builtin_convertvector(c3.h, f8);
    acc += __builtin_convertvector(c4.h, f8);
    acc += __builtin_convertvector(c5.h, f8);
    acc += __builtin_convertvector(c6.h, f8);
    acc *= (1.0f / 7.0f);

    float* o = out + (size_t)(g * RG) * V_OUT + v;
    #pragma unroll
    for (int rr = 0; rr < 8; ++rr)
        __builtin_nontemporal_store(acc[rr], o + (size_t)rr * V_OUT);
}

// ---------------- fallback (v1): direct gather, no workspace ----------------
constexpr int RPB  = 2;
constexpr int RGS  = ROWS / RPB;
constexpr int RG_PER_XCD = RGS / 8;
constexpr int VB1  = (V_OUT + TPB - 1) / TPB;
constexpr int BLOCKS_V1  = RGS * VB1;

__global__ __launch_bounds__(TPB) void icopool_gather(
    const float* __restrict__ x,
    const int*   __restrict__ nidx,
    float*       __restrict__ out)
{
    const int b        = blockIdx.x;
    const int xcd      = b & 7;
    const int j        = b >> 3;
    const int rg_local = j / VB1;
    const int vb       = j % VB1;
    const int rg       = xcd * RG_PER_XCD + rg_local;
    const int r0       = rg * RPB;

    const int v = vb * TPB + threadIdx.x;
    if (v >= V_OUT) return;

    const int base = v * K;
    const int i0 = nidx[base + 0];
    const int i1 = nidx[base + 1];
    const int i2 = nidx[base + 2];
    const int i3 = nidx[base + 3];
    const int i4 = nidx[base + 4];
    const int i5 = nidx[base + 5];
    const int i6 = nidx[base + 6];

    #pragma unroll
    for (int r = 0; r < RPB; ++r) {
        const float* xr = x + (size_t)(r0 + r) * V_IN;
        float sum = xr[i0] + xr[i1] + xr[i2] + xr[i3] + xr[i4] + xr[i5] + xr[i6];
        __builtin_nontemporal_store(sum * (1.0f / 7.0f),
                                    out + (size_t)(r0 + r) * V_OUT + v);
    }
}

extern "C" void kernel_launch(void* const* d_in, const int* in_sizes, int n_in,
                              void* d_out, int out_size, void* d_ws, size_t ws_size,
                              hipStream_t stream) {
    const float* x    = (const float*)d_in[0];
    const int*   nidx = (const int*)d_in[1];
    float*       out  = (float*)d_out;

    if (ws_size >= XH_BYTES && d_ws != nullptr) {
        u4* xH = (u4*)d_ws;
        icopool_pack_h8<<<dim3(IBX, NG), dim3(TPB), 0, stream>>>(x, xH);
        icopool_gather_h8<<<dim3(BLOCKS2), dim3(TPB), 0, stream>>>(xH, nidx, out);
    } else {
        icopool_gather<<<dim3(BLOCKS_V1), dim3(TPB), 0, stream>>>(x, nidx, out);
    }
}